// Round 2
// baseline (566.890 us; speedup 1.0000x reference)
//
#include <hip/hip_runtime.h>
#include <math.h>

#define NB 32
#define NT 512
#define NC 4233
#define NU 64
#define LABT 129            // 2*NU+1
#define PADV (-3.4028234663852886e38f)   // float32 min (matches jnp.finfo(f32).min)
#define EMIT_N (NB * NT * LABT)

// ---------------------------------------------------------------------------
// Kernel 0: massively-parallel emission gather (prep folded in).
// emitP[b][t][j] = logit[b][t][ext_col(j)]   for j = 0..127  (pairs for lanes)
// emitL[b][t]    = logit[b][t][ext_col(128)] (always the blank column)
// ---------------------------------------------------------------------------
__global__ __launch_bounds__(256)
void ctc_gather_kernel(const float* __restrict__ logit,   // [B][T][C]
                       const int*   __restrict__ label,   // [U][B]
                       const int*   __restrict__ blank_ptr,
                       float*       __restrict__ emitP,   // [B][T][128]
                       float*       __restrict__ emitL)   // [B][T]
{
    int tid = blockIdx.x * 256 + threadIdx.x;
    if (tid >= EMIT_N) return;
    int bt = tid / LABT;             // b*NT + t
    int j  = tid - bt * LABT;
    int b  = bt / NT;
    int blank = blank_ptr[0];
    int col;
    if (j & 1) {
        int raw = label[((j - 1) >> 1) * NB + b];
        int ev  = (raw == blank) ? -1 : raw;
        col = ev % NC;                 // python floor-mod for -1 pad labels
        if (col < 0) col += NC;
    } else {
        col = blank;
    }
    float v = logit[(size_t)bt * NC + col];
    if (j < 128) emitP[(size_t)bt * 128 + j] = v;
    else         emitL[bt] = v;
}

// ---------------------------------------------------------------------------
// Kernel 1: single-wave DP scan (no LDS / no barriers in the recurrence).
// Lane l holds dp[2l], dp[2l+1]; lane 63 additionally dp[128].
// Cross-lane need per step is only dp[2l-1]  ->  ONE __shfl_up.
// ---------------------------------------------------------------------------
__global__ __launch_bounds__(64)
void ctc_scan_kernel(const float* __restrict__ emitP,  // [B][T][128]
                     const float* __restrict__ emitL,  // [B][T]
                     const int*   __restrict__ label,  // [U][B]
                     const int*   __restrict__ blank_ptr,
                     float* __restrict__ out,          // [B][T][LABT] align
                     float* __restrict__ loss_out)     // [B]
{
    __shared__ __align__(16) unsigned long long bpm[NT][4]; // even,odd0,odd1,last
    __shared__ int   wl[NT];
    __shared__ float fdp[132];

    const int b = blockIdx.x;
    const int l = threadIdx.x;
    const int blank = blank_ptr[0];

    // label-derived state (prep folded in)
    int raw = label[l * NB + b];
    unsigned long long nbmask = __ballot(raw != blank);
    const int Y = 2 * (int)__popcll(nbmask) + 1;
    int ev  = (raw == blank) ? -1 : raw;
    int pev = __shfl_up(ev, 1);
    if (l == 0) pev = -1;
    const bool cndO = (ev == blank) || (ev == pev);   // cond for odd j=2l+1

    const float2* ep = (const float2*)(emitP + (size_t)b * NT * 128) + l;
    const float*  el = emitL + (size_t)b * NT;

    // t = 0 init
    float2 e00 = ep[0];
    float v0 = (l == 0) ? e00.x : PADV;   // dp[2l]
    float v1 = (l == 0) ? e00.y : PADV;   // dp[2l+1]
    float v2 = PADV;                      // dp[128] (lane 63 meaningful)

    // 4-deep prefetch ring
    float2 r0 = ep[1 * 64], r1 = ep[2 * 64], r2 = ep[3 * 64], r3 = ep[4 * 64];
    float  q0 = el[1], q1 = el[2], q2 = el[3], q3 = el[4];

#define STEP(tcur, rr, qq, tload)                                              \
    do {                                                                       \
        float u1 = __shfl_up(v1, 1);                                           \
        u1 = (l == 0) ? PADV : u1;            /* dp[2l-1] */                   \
        /* even j=2l: 2-way lse (bit-exact 1-exp form) */                      \
        float mE   = fmaxf(v0, u1);                                            \
        float lseE = mE + logf(1.0f + expf(-fabsf(v0 - u1)));                  \
        unsigned long long bE = __ballot(v0 < u1);                             \
        /* odd j=2l+1: 3-way lse, exact rounds-0/1 expression */               \
        float c2e = cndO ? PADV : u1;                                          \
        float mO  = fmaxf(fmaxf(v1, v0), c2e);                                 \
        float lseO = mO + logf(expf(v1 - mO) + expf(v0 - mO) + expf(c2e - mO));\
        unsigned long long gAB = __ballot(v1 >= v0);                           \
        unsigned long long gAC = __ballot(v1 >= c2e);                          \
        unsigned long long gBC = __ballot(v0 >= c2e);                          \
        /* j=128: 2-way lse on lane63's (v2, v1) */                            \
        float mL   = fmaxf(v2, v1);                                            \
        float lseL = mL + logf(1.0f + expf(-fabsf(v2 - v1)));                  \
        unsigned long long bL = __ballot(v2 < v1);                             \
        v0 = rr.x + lseE;                                                      \
        v1 = rr.y + lseO;                                                      \
        v2 = qq   + lseL;                                                      \
        if (l == 0) {                                                          \
            unsigned long long t0m = gAB & gAC;                                \
            bpm[tcur][0] = bE;                                                 \
            bpm[tcur][1] = ~t0m & gBC;                                         \
            bpm[tcur][2] = ~t0m & ~gBC;                                        \
            bpm[tcur][3] = (bL >> 63);                                         \
        }                                                                      \
        if ((tload) < NT) { rr = ep[(tload) * 64]; qq = el[(tload)]; }         \
    } while (0)

    int t = 1;
    for (; t + 3 < NT; t += 4) {
        STEP(t,     r0, q0, t + 4);
        STEP(t + 1, r1, q1, t + 5);
        STEP(t + 2, r2, q2, t + 6);
        STEP(t + 3, r3, q3, t + 7);
    }
    // tail: t = 509, 510, 511
    STEP(t,     r0, q0, NT);
    STEP(t + 1, r1, q1, NT);
    STEP(t + 2, r2, q2, NT);
#undef STEP

    // publish final dp row
    fdp[2 * l]     = v0;
    fdp[2 * l + 1] = v1;
    if (l == 63) fdp[128] = v2;
    __syncthreads();

    // zero-fill align output (overlaps with lane0 backtrack drain)
    float* outA = out + (size_t)b * (NT * LABT);
    {
        float4 z4; z4.x = 0.f; z4.y = 0.f; z4.z = 0.f; z4.w = 0.f;
        float4* o4 = (float4*)outA;
        for (int p = l; p < (NT * LABT) / 4; p += 64) o4[p] = z4;
    }

    // loss + register-ring Viterbi backtrack (lane 0)
    if (l == 0) {
        int i2 = Y - 2; if (i2 < 0) i2 += LABT;   // python wrap for yl==1
        float d1 = fdp[Y - 1];
        float d2 = fdp[i2];
        float mm = fmaxf(d1, d2);
        float la = mm + logf(expf(d1 - mm) + expf(d2 - mm));
        loss_out[b] = -la * 2.0f / (float)(Y - 1);

        int w = (d1 > d2) ? (Y - 1) : i2;
        const ulonglong2* bp2 = (const ulonglong2*)&bpm[0][0];  // 2 per row

#define BLOAD(qa, qb, row) do { qa = bp2[2 * (row)]; qb = bp2[2 * (row) + 1]; } while (0)
#define BPROC(qa, qb, row) do {                                                \
        wl[row] = w;                                                           \
        int lw_ = w >> 1;                                                      \
        int dE_ = (w == 128) ? (int)qb.y : (int)((qa.x >> lw_) & 1ULL);        \
        int dO_ = (int)((qa.y >> lw_) & 1ULL) + 2 * (int)((qb.x >> lw_) & 1ULL);\
        w -= (w & 1) ? dO_ : dE_;                                              \
    } while (0)

        ulonglong2 a0, b0, a1, b1, a2, b2, a3, b3;
        BLOAD(a0, b0, NT - 1);
        BLOAD(a1, b1, NT - 2);
        BLOAD(a2, b2, NT - 3);
        BLOAD(a3, b3, NT - 4);
        int tt;
        for (tt = NT - 1; tt >= 8; tt -= 4) {
            BPROC(a0, b0, tt    ); BLOAD(a0, b0, tt - 4);
            BPROC(a1, b1, tt - 1); BLOAD(a1, b1, tt - 5);
            BPROC(a2, b2, tt - 2); BLOAD(a2, b2, tt - 6);
            BPROC(a3, b3, tt - 3); BLOAD(a3, b3, tt - 7);
        }
        // slots now hold rows 7,6,5,4
        BPROC(a0, b0, 7); BLOAD(a0, b0, 3);
        BPROC(a1, b1, 6); BLOAD(a1, b1, 2);
        BPROC(a2, b2, 5); BLOAD(a2, b2, 1);
        BPROC(a3, b3, 4);
        BPROC(a0, b0, 3);
        BPROC(a1, b1, 2);
        BPROC(a2, b2, 1);
        wl[0] = w;   // bp at t=0 is identity
#undef BLOAD
#undef BPROC
    }
    __syncthreads();   // drain zero stores + publish wl

    // scatter the ones
    for (int t2 = l; t2 < NT; t2 += 64)
        outA[(size_t)t2 * LABT + wl[t2]] = 1.0f;
}

// ---------------------------------------------------------------------------
extern "C" void kernel_launch(void* const* d_in, const int* in_sizes, int n_in,
                              void* d_out, int out_size, void* d_ws, size_t ws_size,
                              hipStream_t stream)
{
    const float* logit = (const float*)d_in[0];
    const int*   label = (const int*)d_in[1];
    const int*   blank = (const int*)d_in[2];

    float* out = (float*)d_out;   // [B*T*LABT] align (0/1 float) then [B] loss

    float* emitP = (float*)d_ws;                       // 32*512*128 floats = 8.39 MB
    float* emitL = emitP + (size_t)NB * NT * 128;      // 32*512 floats

    ctc_gather_kernel<<<(EMIT_N + 255) / 256, 256, 0, stream>>>(
        logit, label, blank, emitP, emitL);
    ctc_scan_kernel<<<NB, 64, 0, stream>>>(
        emitP, emitL, label, blank, out, out + (size_t)NB * NT * LABT);
}

// Round 3
// 542.326 us; speedup vs baseline: 1.0453x; 1.0453x over previous
//
#include <hip/hip_runtime.h>
#include <math.h>

#define NB 32
#define NT 512
#define NC 4233
#define NU 64
#define LABT 129            // 2*NU+1
#define PADV (-3.4028234663852886e38f)   // float32 min (matches jnp.finfo(f32).min)
#define EMITP_N (NB * NT * 128)

// ---------------------------------------------------------------------------
// Kernel 0: massively-parallel emission gather (prep folded in).
// emitP[b][t][j] = logit[b][t][ext_col(j)]   for j = 0..127.
// NOTE: ext_col(128) == blank == ext_col(0), so the last DP column's emission
// is identical to column 0 -- recovered in the scan via readfirstlane.
// ---------------------------------------------------------------------------
__global__ __launch_bounds__(256)
void ctc_gather_kernel(const float* __restrict__ logit,   // [B][T][C]
                       const int*   __restrict__ label,   // [U][B]
                       const int*   __restrict__ blank_ptr,
                       float*       __restrict__ emitP)   // [B][T][128]
{
    int tid = blockIdx.x * 256 + threadIdx.x;
    if (tid >= EMITP_N) return;
    int bt = tid >> 7;               // b*NT + t
    int j  = tid & 127;
    int b  = bt / NT;
    int blank = blank_ptr[0];
    int col;
    if (j & 1) {
        int raw = label[((j - 1) >> 1) * NB + b];
        int ev  = (raw == blank) ? -1 : raw;
        col = ev % NC;                 // python floor-mod for -1 pad labels
        if (col < 0) col += NC;
    } else {
        col = blank;
    }
    emitP[tid] = logit[(size_t)bt * NC + col];
}

// ---------------------------------------------------------------------------
// Cross-lane shift-by-1 via DPP wave_shr:1 -- pure VALU, no lgkmcnt.
// lane l gets x[l-1]; lane 0 gets `fill`.
// ---------------------------------------------------------------------------
__device__ __forceinline__ float dpp_wave_shr1(float x, float fill) {
    return __int_as_float(__builtin_amdgcn_update_dpp(
        __float_as_int(fill), __float_as_int(x), 0x138 /*wave_shr:1*/,
        0xf, 0xf, false));
}

// ---------------------------------------------------------------------------
// Kernel 1: single-wave DP scan.  Loop body contains NO lgkm-dependent ops:
// one float2 VMEM load (8-deep ring, counted vmcnt), DPP for the cross-lane
// value, readfirstlane for e[128], ballots to SGPRs, masked ds_writes
// (fire-and-forget).  Lane l holds dp[2l], dp[2l+1]; lane 63 also dp[128].
// ---------------------------------------------------------------------------
__global__ __launch_bounds__(64)
void ctc_scan_kernel(const float* __restrict__ emitP,  // [B][T][128]
                     const int*   __restrict__ label,  // [U][B]
                     const int*   __restrict__ blank_ptr,
                     float* __restrict__ out,          // [B][T][LABT] align
                     float* __restrict__ loss_out)     // [B]
{
    __shared__ __align__(16) unsigned long long bpm[NT][4]; // even,odd0,odd1,last
    __shared__ int   wl[NT];
    __shared__ float fdp[132];

    const int b = blockIdx.x;
    const int l = threadIdx.x;
    const int blank = blank_ptr[0];

    // label-derived state (prep folded in)
    int raw = label[l * NB + b];
    unsigned long long nbmask = __ballot(raw != blank);
    const int Y = 2 * (int)__popcll(nbmask) + 1;
    int ev  = (raw == blank) ? -1 : raw;
    int pev = __shfl_up(ev, 1);
    if (l == 0) pev = -1;
    const bool cndO = (ev == blank) || (ev == pev);   // cond for odd j=2l+1

    const float2* ep = (const float2*)(emitP + (size_t)b * NT * 128) + l;

    // t = 0 init
    float2 e00 = ep[0];
    float v0 = (l == 0) ? e00.x : PADV;   // dp[2l]
    float v1 = (l == 0) ? e00.y : PADV;   // dp[2l+1]
    float v2 = PADV;                      // dp[128] (lane 63 meaningful)

    // 8-deep prefetch ring (covers ~900cy HBM/L3 latency at ~150cy/step)
    float2 r0 = ep[1 * 64], r1 = ep[2 * 64], r2 = ep[3 * 64], r3 = ep[4 * 64];
    float2 r4 = ep[5 * 64], r5 = ep[6 * 64], r6 = ep[7 * 64], r7 = ep[8 * 64];

#define STEP(tcur, rr, tload)                                                  \
    do {                                                                       \
        float u1 = dpp_wave_shr1(v1, PADV);   /* dp[2l-1] */                   \
        /* even j=2l: 2-way lse (bit-exact 1-exp form) */                      \
        float mE   = fmaxf(v0, u1);                                            \
        float lseE = mE + logf(1.0f + expf(-fabsf(v0 - u1)));                  \
        unsigned long long bE = __ballot(v0 < u1);                             \
        /* odd j=2l+1: 3-way lse, exact rounds-0/1/2 expression */             \
        float c2e = cndO ? PADV : u1;                                          \
        float mO  = fmaxf(fmaxf(v1, v0), c2e);                                 \
        float lseO = mO + logf(expf(v1 - mO) + expf(v0 - mO) + expf(c2e - mO));\
        unsigned long long gAB = __ballot(v1 >= v0);                           \
        unsigned long long gAC = __ballot(v1 >= c2e);                          \
        unsigned long long gBC = __ballot(v0 >= c2e);                          \
        /* j=128: 2-way lse on lane63's (v2, v1) */                            \
        float mL   = fmaxf(v2, v1);                                            \
        float lseL = mL + logf(1.0f + expf(-fabsf(v2 - v1)));                  \
        unsigned long long bL = __ballot(v2 < v1);                             \
        /* e[128] == e[0] == lane0's rr.x (blank column) */                    \
        float eL = __int_as_float(                                             \
            __builtin_amdgcn_readfirstlane(__float_as_int(rr.x)));             \
        v0 = rr.x + lseE;                                                      \
        v1 = rr.y + lseO;                                                      \
        v2 = eL   + lseL;                                                      \
        if (l == 0) {                                                          \
            unsigned long long t0m = gAB & gAC;                                \
            bpm[tcur][0] = bE;                                                 \
            bpm[tcur][1] = ~t0m & gBC;                                         \
            bpm[tcur][2] = ~t0m & ~gBC;                                        \
            bpm[tcur][3] = (bL >> 63);                                         \
        }                                                                      \
        if ((tload) < NT) rr = ep[(tload) * 64];                               \
    } while (0)

    int t = 1;
    for (; t + 7 < NT; t += 8) {
        STEP(t,     r0, t + 8);
        STEP(t + 1, r1, t + 9);
        STEP(t + 2, r2, t + 10);
        STEP(t + 3, r3, t + 11);
        STEP(t + 4, r4, t + 12);
        STEP(t + 5, r5, t + 13);
        STEP(t + 6, r6, t + 14);
        STEP(t + 7, r7, t + 15);
    }
    // tail: t = 505..511
    STEP(t,     r0, NT);
    STEP(t + 1, r1, NT);
    STEP(t + 2, r2, NT);
    STEP(t + 3, r3, NT);
    STEP(t + 4, r4, NT);
    STEP(t + 5, r5, NT);
    STEP(t + 6, r6, NT);
#undef STEP

    // publish final dp row
    fdp[2 * l]     = v0;
    fdp[2 * l + 1] = v1;
    if (l == 63) fdp[128] = v2;
    __syncthreads();

    // zero-fill align output (overlaps with lane0 backtrack drain)
    float* outA = out + (size_t)b * (NT * LABT);
    {
        float4 z4; z4.x = 0.f; z4.y = 0.f; z4.z = 0.f; z4.w = 0.f;
        float4* o4 = (float4*)outA;
        for (int p = l; p < (NT * LABT) / 4; p += 64) o4[p] = z4;
    }

    // loss + register-ring Viterbi backtrack (lane 0)
    if (l == 0) {
        int i2 = Y - 2; if (i2 < 0) i2 += LABT;   // python wrap for yl==1
        float d1 = fdp[Y - 1];
        float d2 = fdp[i2];
        float mm = fmaxf(d1, d2);
        float la = mm + logf(expf(d1 - mm) + expf(d2 - mm));
        loss_out[b] = -la * 2.0f / (float)(Y - 1);

        int w = (d1 > d2) ? (Y - 1) : i2;
        const ulonglong2* bp2 = (const ulonglong2*)&bpm[0][0];  // 2 per row

#define BLOAD(qa, qb, row) do { qa = bp2[2 * (row)]; qb = bp2[2 * (row) + 1]; } while (0)
#define BPROC(qa, qb, row) do {                                                \
        wl[row] = w;                                                           \
        int lw_ = w >> 1;                                                      \
        int dE_ = (w == 128) ? (int)qb.y : (int)((qa.x >> lw_) & 1ULL);        \
        int dO_ = (int)((qa.y >> lw_) & 1ULL) + 2 * (int)((qb.x >> lw_) & 1ULL);\
        w -= (w & 1) ? dO_ : dE_;                                              \
    } while (0)

        ulonglong2 a0, b0, a1, b1, a2, b2, a3, b3;
        BLOAD(a0, b0, NT - 1);
        BLOAD(a1, b1, NT - 2);
        BLOAD(a2, b2, NT - 3);
        BLOAD(a3, b3, NT - 4);
        int tt;
        for (tt = NT - 1; tt >= 8; tt -= 4) {
            BPROC(a0, b0, tt    ); BLOAD(a0, b0, tt - 4);
            BPROC(a1, b1, tt - 1); BLOAD(a1, b1, tt - 5);
            BPROC(a2, b2, tt - 2); BLOAD(a2, b2, tt - 6);
            BPROC(a3, b3, tt - 3); BLOAD(a3, b3, tt - 7);
        }
        // slots now hold rows 7,6,5,4
        BPROC(a0, b0, 7); BLOAD(a0, b0, 3);
        BPROC(a1, b1, 6); BLOAD(a1, b1, 2);
        BPROC(a2, b2, 5); BLOAD(a2, b2, 1);
        BPROC(a3, b3, 4);
        BPROC(a0, b0, 3);
        BPROC(a1, b1, 2);
        BPROC(a2, b2, 1);
        wl[0] = w;   // bp at t=0 is identity
#undef BLOAD
#undef BPROC
    }
    __syncthreads();   // drain zero stores + publish wl

    // scatter the ones
    for (int t2 = l; t2 < NT; t2 += 64)
        outA[(size_t)t2 * LABT + wl[t2]] = 1.0f;
}

// ---------------------------------------------------------------------------
extern "C" void kernel_launch(void* const* d_in, const int* in_sizes, int n_in,
                              void* d_out, int out_size, void* d_ws, size_t ws_size,
                              hipStream_t stream)
{
    const float* logit = (const float*)d_in[0];
    const int*   label = (const int*)d_in[1];
    const int*   blank = (const int*)d_in[2];

    float* out = (float*)d_out;   // [B*T*LABT] align (0/1 float) then [B] loss

    float* emitP = (float*)d_ws;  // 32*512*128 floats = 8.39 MB

    ctc_gather_kernel<<<EMITP_N / 256, 256, 0, stream>>>(
        logit, label, blank, emitP);
    ctc_scan_kernel<<<NB, 64, 0, stream>>>(
        emitP, label, blank, out, out + (size_t)NB * NT * LABT);
}